// Round 2
// baseline (986.498 us; speedup 1.0000x reference)
//
#include <hip/hip_runtime.h>
#include <math.h>

// Single-query attention, fused flash-decode, fp32.
// B=32, S=4096, D=1024. Memory-bound: K+V = 1.074 GB streamed from HBM.
#define BB 32
#define SS 4096
#define DD 1024
#define CHUNKS 32
#define CHUNK_S (SS / CHUNKS)     // 128 keys per block
#define KPW (CHUNK_S / 4)         // 32 keys per wave
#define SCALE 0.03125f            // 1/sqrt(1024)

// Kernel 1: per (b, chunk) partial attention, single fused pass.
// block = 256 threads = 4 waves. Wave w owns keys [w*KPW, (w+1)*KPW).
// Each lane holds 16 floats of D (d = 4*lane + 256*j, j=0..3).
__global__ __launch_bounds__(256) void attn_partial(
    const float* __restrict__ q,      // [B, D]
    const float* __restrict__ k,      // [B, S, D]
    const float* __restrict__ v,      // [B, S, D]
    const int*   __restrict__ mask,   // [B, S]
    float* __restrict__ part_o,       // [B, CHUNKS, D] (unnormalized)
    float* __restrict__ part_ml)      // [B, CHUNKS, 2] (m, l)
{
    const int c    = blockIdx.x;
    const int b    = blockIdx.y;
    const int tid  = threadIdx.x;
    const int lane = tid & 63;
    const int wave = tid >> 6;   // 0..3

    __shared__ float s_o[4 * DD];          // 16 KB: per-wave unnormalized O
    __shared__ float s_m[4], s_l[4];
    __shared__ int   s_mask[CHUNK_S];

    const int s0 = c * CHUNK_S;

    // Preload mask chunk (coalesced).
    if (tid < CHUNK_S) s_mask[tid] = mask[(size_t)b * SS + s0 + tid];

    // Q fragment.
    const float* qb = q + (size_t)b * DD;
    float4 qf[4];
#pragma unroll
    for (int j = 0; j < 4; ++j)
        qf[j] = *(const float4*)(qb + 4 * lane + 256 * j);

    __syncthreads();   // s_mask ready

    // --- Fused online-softmax pass over this wave's 32 keys ---
    const size_t base = ((size_t)b * SS + s0 + wave * KPW) * DD;
    const float* kp = k + base + 4 * lane;
    const float* vp = v + base + 4 * lane;

    float m = -1e30f;
    float l = 0.f;
    float4 o[4] = {{0,0,0,0},{0,0,0,0},{0,0,0,0},{0,0,0,0}};

#pragma unroll 2
    for (int i = 0; i < KPW; ++i) {
        if (s_mask[wave * KPW + i] != 0) {          // wave-uniform branch
            // dot(q, k_row): 4 x float4 per lane, 64-lane butterfly reduce
            float acc = 0.f;
#pragma unroll
            for (int j = 0; j < 4; ++j) {
                float4 kf = *(const float4*)(kp + 256 * j);
                acc += qf[j].x * kf.x + qf[j].y * kf.y + qf[j].z * kf.z + qf[j].w * kf.w;
            }
#pragma unroll
            for (int off = 32; off > 0; off >>= 1)
                acc += __shfl_xor(acc, off, 64);
            const float sc = acc * SCALE;           // wave-uniform

            if (sc > m) {                           // wave-uniform: rescale
                const float alpha = __expf(m - sc);
                l *= alpha;
#pragma unroll
                for (int j = 0; j < 4; ++j) {
                    o[j].x *= alpha; o[j].y *= alpha;
                    o[j].z *= alpha; o[j].w *= alpha;
                }
                m = sc;
            }
            const float w = __expf(sc - m);
            l += w;
#pragma unroll
            for (int j = 0; j < 4; ++j) {
                const float4 vf = *(const float4*)(vp + 256 * j);
                o[j].x += w * vf.x; o[j].y += w * vf.y;
                o[j].z += w * vf.z; o[j].w += w * vf.w;
            }
        }
        kp += DD; vp += DD;
    }

    // --- Merge 4 waves via LDS ---
#pragma unroll
    for (int j = 0; j < 4; ++j)
        *(float4*)(s_o + wave * DD + 4 * lane + 256 * j) = o[j];
    if (lane == 0) { s_m[wave] = m; s_l[wave] = l; }
    __syncthreads();

    float M = fmaxf(fmaxf(s_m[0], s_m[1]), fmaxf(s_m[2], s_m[3]));
    float e[4];
#pragma unroll
    for (int w = 0; w < 4; ++w) e[w] = __expf(s_m[w] - M);
    float L = 0.f;
#pragma unroll
    for (int w = 0; w < 4; ++w) L += e[w] * s_l[w];

    // thread owns d = 4*tid .. 4*tid+3
    float4 acc = {0.f, 0.f, 0.f, 0.f};
#pragma unroll
    for (int w = 0; w < 4; ++w) {
        const float4 ow = *(const float4*)(s_o + w * DD + 4 * tid);
        acc.x += e[w] * ow.x; acc.y += e[w] * ow.y;
        acc.z += e[w] * ow.z; acc.w += e[w] * ow.w;
    }
    *(float4*)(part_o + ((size_t)b * CHUNKS + c) * DD + 4 * tid) = acc;
    if (tid == 0) {
        part_ml[((size_t)b * CHUNKS + c) * 2 + 0] = M;
        part_ml[((size_t)b * CHUNKS + c) * 2 + 1] = L;
    }
}

// Kernel 2: combine CHUNKS partials per batch row, normalize.
__global__ __launch_bounds__(256) void attn_combine(
    const float* __restrict__ part_o,   // [B, CHUNKS, D]
    const float* __restrict__ part_ml,  // [B, CHUNKS, 2]
    float* __restrict__ out)            // [B, 1, D]
{
    const int b   = blockIdx.x;
    const int tid = threadIdx.x;

    __shared__ float s_m[CHUNKS];
    __shared__ float s_l[CHUNKS];
    __shared__ float s_scale[CHUNKS];

    if (tid < CHUNKS) {
        s_m[tid] = part_ml[((size_t)b * CHUNKS + tid) * 2 + 0];
        s_l[tid] = part_ml[((size_t)b * CHUNKS + tid) * 2 + 1];
    }
    __syncthreads();

    float m = -1e30f;
#pragma unroll
    for (int c = 0; c < CHUNKS; ++c) m = fmaxf(m, s_m[c]);
    if (tid < CHUNKS) s_scale[tid] = __expf(s_m[tid] - m);
    __syncthreads();

    float L = 0.f;
#pragma unroll
    for (int c = 0; c < CHUNKS; ++c) L += s_l[c] * s_scale[c];
    const float inv_L = 1.f / L;

    float4 acc = {0.f, 0.f, 0.f, 0.f};
    for (int c = 0; c < CHUNKS; ++c) {
        const float sc = s_scale[c];
        const float4 o = *(const float4*)(part_o + ((size_t)b * CHUNKS + c) * DD + 4 * tid);
        acc.x += sc * o.x;
        acc.y += sc * o.y;
        acc.z += sc * o.z;
        acc.w += sc * o.w;
    }
    acc.x *= inv_L; acc.y *= inv_L; acc.z *= inv_L; acc.w *= inv_L;
    *(float4*)(out + (size_t)b * DD + 4 * tid) = acc;
}

extern "C" void kernel_launch(void* const* d_in, const int* in_sizes, int n_in,
                              void* d_out, int out_size, void* d_ws, size_t ws_size,
                              hipStream_t stream) {
    const float* q    = (const float*)d_in[0];
    const float* k    = (const float*)d_in[1];
    const float* v    = (const float*)d_in[2];
    const int*   mask = (const int*)d_in[3];
    float* out = (float*)d_out;

    float* part_o  = (float*)d_ws;
    float* part_ml = part_o + (size_t)BB * CHUNKS * DD;

    dim3 grid1(CHUNKS, BB);
    attn_partial<<<grid1, 256, 0, stream>>>(q, k, v, mask, part_o, part_ml);
    attn_combine<<<BB, 256, 0, stream>>>(part_o, part_ml, out);
}